// Round 9
// baseline (383.896 us; speedup 1.0000x reference)
//
#include <hip/hip_runtime.h>
#include <hip/hip_bf16.h>
#include <stdint.h>

// DequantingLinear: out[TOK,OUT] = x[TOK,IN] @ dequant(w_q,w_scales)^T + bias
// R9: occupancy experiment. 256x128 tile, BK=32, 48KB LDS -> 2 blocks/CU
// (16 waves, 4/SIMD). Wave out 64x64 (acc=64 VGPR) fits 128-VGPR budget.
// Cross-block TLP covers barrier/wait bubbles that capped 1-block/CU at 43%.

typedef __bf16 bf16;
typedef __bf16 bf16x8 __attribute__((ext_vector_type(8)));
typedef float f32x4 __attribute__((ext_vector_type(4)));

#define AS1 __attribute__((address_space(1)))
#define AS3 __attribute__((address_space(3)))

__device__ __forceinline__ void gload_lds16(const void* g, void* l) {
    __builtin_amdgcn_global_load_lds((AS1 void*)g, (AS3 void*)l, 16, 0, 0);
}

#define MFMA16(d, x, y) d = __builtin_amdgcn_mfma_f32_16x16x32_bf16(x, y, d, 0, 0, 0)

// ---------------- Pass 1a: dequantize w_q (int32) * scale -> bf16 ----------
__global__ __launch_bounds__(128) void k_dequant(
    const int* __restrict__ q, const float* __restrict__ sc,
    bf16* __restrict__ w, int IN) {
    const int row = blockIdx.y;
    const int k = (blockIdx.x * 128 + threadIdx.x) * 8;
    if (k >= IN) return;
    const float s = sc[(size_t)row * (IN >> 5) + (k >> 5)];
    const size_t base = (size_t)row * IN + k;
    const int4 q0 = *(const int4*)(q + base);
    const int4 q1 = *(const int4*)(q + base + 4);
    bf16x8 o;
    o[0] = (bf16)(q0.x * s); o[1] = (bf16)(q0.y * s);
    o[2] = (bf16)(q0.z * s); o[3] = (bf16)(q0.w * s);
    o[4] = (bf16)(q1.x * s); o[5] = (bf16)(q1.y * s);
    o[6] = (bf16)(q1.z * s); o[7] = (bf16)(q1.w * s);
    *(bf16x8*)(w + base) = o;
}

// ---------------- Pass 1b: x f32 -> bf16 -----------------------------------
__global__ __launch_bounds__(256) void k_cvt(
    const float* __restrict__ x, bf16* __restrict__ xb, long long n8) {
    long long i = (long long)blockIdx.x * 256 + threadIdx.x;
    const long long stride = (long long)gridDim.x * 256;
    for (; i < n8; i += stride) {
        const float4 a = *(const float4*)(x + i * 8);
        const float4 b = *(const float4*)(x + i * 8 + 4);
        bf16x8 o;
        o[0] = (bf16)a.x; o[1] = (bf16)a.y; o[2] = (bf16)a.z; o[3] = (bf16)a.w;
        o[4] = (bf16)b.x; o[5] = (bf16)b.y; o[6] = (bf16)b.z; o[7] = (bf16)b.w;
        *(bf16x8*)(xb + i * 8) = o;
    }
}

// ---------------- Pass 2: 256x128 bf16 GEMM, BK=32, 2 blocks/CU ------------
// 512 thr = 8 waves (wm=wv>>1 in 0..3, wn=wv&1); wave out 64x64; acc[4][4].
// LDS 48KB: buf0 {A@0 16KB, B@16384 8KB}, buf1 @24576. Unit layout (R6-
// verified): (frow,c4) -> LDSrow=frow>>1, chunk=(((frow&1)<<2)|c4)^(LDSrow&7),
// byte=LDSrow*128+chunk*16. Per phase (1 K-tile): 8 ds_read_b128 + 3 gloads
// -> BAR -> lgkm0 -> 16 MFMA -> vmcnt(0) -> BAR.
__global__ __launch_bounds__(512, 4) void k_gemm2b(
    const bf16* __restrict__ A, const bf16* __restrict__ B,
    const float* __restrict__ bias, float* __restrict__ C,
    int M, int N, int K) {
    __shared__ __align__(16) char lds[49152];
    const int tid = threadIdx.x;
    const int wv = tid >> 6, ln = tid & 63;
    const int wm = wv >> 1, wn = wv & 1;
    const int nbn = N >> 7;
    const int nwg = gridDim.x;
    const int q8 = nwg >> 3, r8 = nwg & 7;
    const int xcd = blockIdx.x & 7, lin = blockIdx.x >> 3;
    const int swz = (xcd < r8 ? xcd * (q8 + 1)
                              : r8 * (q8 + 1) + (xcd - r8) * q8) + lin;
    const int bm = swz / nbn, bn = swz % nbn;

    const size_t rowb = (size_t)K * 2;
    // staging source map (inverse swizzle; R6-verified): slot L -> (frow,c4)
    const int L0 = tid, L1 = tid + 512;
    const int x0 = (L0 & 7) ^ ((L0 >> 3) & 7);
    const int x1 = (L1 & 7) ^ ((L1 >> 3) & 7);
    const int fr0 = ((L0 >> 3) << 1) | (x0 >> 2), c40 = x0 & 3;
    const int fr1 = ((L1 >> 3) << 1) | (x1 >> 2), c41 = x1 & 3;
    const char* Asrc0 = (const char*)A + ((size_t)(bm << 8) + fr0) * rowb + c40 * 16;
    const char* Asrc1 = (const char*)A + ((size_t)(bm << 8) + fr1) * rowb + c41 * 16;
    const char* Bsrc0 = (const char*)B + ((size_t)(bn << 7) + fr0) * rowb + c40 * 16;
    const int ldsw = wv << 10;

    // stage tile kt (cols kt..kt+31) into buf at byte bb_: A 2 gloads, B 1
#define STGA(bb_, kt_) do {                                                   \
        const size_t kb_ = (size_t)(kt_) << 1;                                \
        gload_lds16(Asrc0 + kb_, lds + (bb_) + ldsw);                         \
        gload_lds16(Asrc1 + kb_, lds + (bb_) + 8192 + ldsw);                  \
    } while (0)
#define STGB(bb_, kt_) do {                                                   \
        const size_t kb_ = (size_t)(kt_) << 1;                                \
        gload_lds16(Bsrc0 + kb_, lds + (bb_) + 16384 + ldsw);                 \
    } while (0)

    // ds_read addressing (R6-verified): chunk per-lane constant
    const int chunk = (((ln & 1) << 2) | (ln >> 4)) ^ ((ln >> 1) & 7);
    const int aoff = (wm << 12) + (((ln & 15) >> 1) << 7) + (chunk << 4);
    const int boff = 16384 + (wn << 12) + (((ln & 15) >> 1) << 7) + (chunk << 4);

    f32x4 acc[4][4] = {};

#define BAR __builtin_amdgcn_s_barrier()
#define VMW0 asm volatile("s_waitcnt vmcnt(0)" ::: "memory")
#define LGK0 do { asm volatile("s_waitcnt lgkmcnt(0)" ::: "memory");          \
                  __builtin_amdgcn_sched_barrier(0); } while (0)

    // phase: read frags of buf rb_, optionally stage next tile into sb_
#define PHASE(rb_, STAGE_STMT, ENDW_STMT) do {                                \
        bf16x8 pa_[4], pb_[4];                                                \
        _Pragma("unroll")                                                     \
        for (int m = 0; m < 4; ++m)                                           \
            pa_[m] = *(const bf16x8*)(lds + (rb_) + aoff + (m << 10));        \
        _Pragma("unroll")                                                     \
        for (int n = 0; n < 4; ++n)                                           \
            pb_[n] = *(const bf16x8*)(lds + (rb_) + boff + (n << 10));        \
        STAGE_STMT;                                                           \
        BAR;                                                                  \
        LGK0;                                                                 \
        __builtin_amdgcn_s_setprio(1);                                        \
        _Pragma("unroll")                                                     \
        for (int m = 0; m < 4; ++m)                                           \
            _Pragma("unroll")                                                 \
            for (int n = 0; n < 4; ++n)                                       \
                MFMA16(acc[m][n], pa_[m], pb_[n]);                            \
        __builtin_amdgcn_s_setprio(0);                                        \
        ENDW_STMT;                                                            \
        BAR;                                                                  \
    } while (0)

    // ---- prologue: tile0 -> buf0
    STGA(0, 0);
    STGB(0, 0);
    VMW0;
    BAR;

    const int NT = K >> 5;          // K/32 tiles, NT even (K%64==0)
    const int NI = NT >> 1;
#pragma unroll 1
    for (int j = 0; j < NI - 1; ++j) {
        const int k1 = (j << 6) + 32, k2 = k1 + 32;
        PHASE(0,     { STGA(24576, k1); STGB(24576, k1); }, VMW0);  // T=2j
        PHASE(24576, { STGA(0,     k2); STGB(0,     k2); }, VMW0);  // T=2j+1
    }
    {   // last pair
        const int k1 = ((NI - 1) << 6) + 32;
        PHASE(0,     { STGA(24576, k1); STGB(24576, k1); }, VMW0);
        PHASE(24576, (void)0, (void)0);
    }
#undef PHASE
#undef STGA
#undef STGB

    // ---- epilogue: D layout col=lane&15, row=(lane>>4)*4+reg
    const int erow = (bm << 8) + (wm << 6) + ((ln >> 4) << 2);
    const int ecol = (bn << 7) + (wn << 6) + (ln & 15);
    float bv[4];
#pragma unroll
    for (int n = 0; n < 4; ++n) bv[n] = bias[ecol + (n << 4)];
#pragma unroll
    for (int m = 0; m < 4; ++m)
#pragma unroll
        for (int r = 0; r < 4; ++r) {
            float* Crow = C + (size_t)(erow + (m << 4) + r) * N + ecol;
#pragma unroll
            for (int n = 0; n < 4; ++n)
                Crow[n << 4] = acc[m][n][r] + bv[n];
        }
}

// ---------------- Fallback: fused dequant+GEMM (no workspace) --------------
__global__ __launch_bounds__(256) void k_fused(
    const float* __restrict__ X, const int* __restrict__ Q,
    const float* __restrict__ SC, const float* __restrict__ bias,
    float* __restrict__ C, int M, int N, int K) {
    __shared__ __align__(16) bf16 sA[128 * 32];
    __shared__ __align__(16) bf16 sB[128 * 32];
    const int tid = threadIdx.x;
    const int wv = tid >> 6;
    const int ln = tid & 63;
    const int nbn = N >> 7;
    const int nwg = gridDim.x;
    const int q8 = nwg >> 3, r8 = nwg & 7;
    const int xcd = blockIdx.x & 7, lin = blockIdx.x >> 3;
    const int swz = (xcd < r8 ? xcd * (q8 + 1)
                              : r8 * (q8 + 1) + (xcd - r8) * q8) + lin;
    const int bm = swz / nbn, bn = swz % nbn;
    const int wr = (wv >> 1) << 6;
    const int wc = (wv & 1) << 6;
    const int srow = tid >> 1;
    const int sk = (tid & 1) << 4;

    f32x4 acc[4][4] = {};
    const float* xrow = X + (size_t)((bm << 7) + srow) * K + sk;
    const int* qrow = Q + (size_t)((bn << 7) + srow) * K + sk;
    const float* scrow = SC + (size_t)((bn << 7) + srow) * (K >> 5);

    for (int kt = 0; kt < K; kt += 32) {
        const float4 a0 = *(const float4*)(xrow + kt);
        const float4 a1 = *(const float4*)(xrow + kt + 4);
        const float4 a2 = *(const float4*)(xrow + kt + 8);
        const float4 a3 = *(const float4*)(xrow + kt + 12);
        const int4 q0 = *(const int4*)(qrow + kt);
        const int4 q1 = *(const int4*)(qrow + kt + 4);
        const int4 q2 = *(const int4*)(qrow + kt + 8);
        const int4 q3 = *(const int4*)(qrow + kt + 12);
        const float s = scrow[(kt + sk) >> 5];
        bf16x8 wa0, wa1, wb0, wb1;
        wa0[0] = (bf16)a0.x; wa0[1] = (bf16)a0.y; wa0[2] = (bf16)a0.z; wa0[3] = (bf16)a0.w;
        wa0[4] = (bf16)a1.x; wa0[5] = (bf16)a1.y; wa0[6] = (bf16)a1.z; wa0[7] = (bf16)a1.w;
        wa1[0] = (bf16)a2.x; wa1[1] = (bf16)a2.y; wa1[2] = (bf16)a2.z; wa1[3] = (bf16)a2.w;
        wa1[4] = (bf16)a3.x; wa1[5] = (bf16)a3.y; wa1[6] = (bf16)a3.z; wa1[7] = (bf16)a3.w;
        wb0[0] = (bf16)(q0.x * s); wb0[1] = (bf16)(q0.y * s);
        wb0[2] = (bf16)(q0.z * s); wb0[3] = (bf16)(q0.w * s);
        wb0[4] = (bf16)(q1.x * s); wb0[5] = (bf16)(q1.y * s);
        wb0[6] = (bf16)(q1.z * s); wb0[7] = (bf16)(q1.w * s);
        wb1[0] = (bf16)(q2.x * s); wb1[1] = (bf16)(q2.y * s);
        wb1[2] = (bf16)(q2.z * s); wb1[3] = (bf16)(q2.w * s);
        wb1[4] = (bf16)(q3.x * s); wb1[5] = (bf16)(q3.y * s);
        wb1[6] = (bf16)(q3.z * s); wb1[7] = (bf16)(q3.w * s);
        __syncthreads();
        *(bf16x8*)(sA + srow * 32 + sk) = wa0;
        *(bf16x8*)(sA + srow * 32 + sk + 8) = wa1;
        *(bf16x8*)(sB + srow * 32 + sk) = wb0;
        *(bf16x8*)(sB + srow * 32 + sk + 8) = wb1;
        __syncthreads();

        bf16x8 af[4], bg[4];
#pragma unroll
        for (int m = 0; m < 4; ++m)
            af[m] = *(const bf16x8*)(sA + ((wr + (m << 4) + (ln & 15)) << 5) +
                                     ((ln >> 4) << 3));
#pragma unroll
        for (int n = 0; n < 4; ++n)
            bg[n] = *(const bf16x8*)(sB + ((wc + (n << 4) + (ln & 15)) << 5) +
                                     ((ln >> 4) << 3));
#pragma unroll
        for (int m = 0; m < 4; ++m)
#pragma unroll
            for (int n = 0; n < 4; ++n)
                acc[m][n] = __builtin_amdgcn_mfma_f32_16x16x32_bf16(
                    af[m], bg[n], acc[m][n], 0, 0, 0);
    }

    float bv[4];
#pragma unroll
    for (int n = 0; n < 4; ++n)
        bv[n] = bias[(bn << 7) + wc + (n << 4) + (ln & 15)];
#pragma unroll
    for (int m = 0; m < 4; ++m) {
        const int grow0 = (bm << 7) + wr + (m << 4) + ((ln >> 4) << 2);
#pragma unroll
        for (int r = 0; r < 4; ++r) {
            float* Crow = C + (size_t)(grow0 + r) * N;
#pragma unroll
            for (int n = 0; n < 4; ++n)
                Crow[(bn << 7) + wc + (n << 4) + (ln & 15)] =
                    acc[m][n][r] + bv[n];
        }
    }
}

extern "C" void kernel_launch(void* const* d_in, const int* in_sizes, int n_in,
                              void* d_out, int out_size, void* d_ws, size_t ws_size,
                              hipStream_t stream) {
    const float* x = (const float*)d_in[0];
    const int* wq = (const int*)d_in[1];
    const float* sc = (const float*)d_in[2];
    const float* bias = (const float*)d_in[3];
    float* out = (float*)d_out;

    const long long xN = in_sizes[0];  // TOK*IN
    const long long wN = in_sizes[1];  // OUT*IN
    const int OUT = in_sizes[3];       // bias length
    const int IN = (int)(wN / OUT);
    const int TOK = (int)(xN / IN);
    const int M = TOK, N = OUT, K = IN;

    const size_t wb_bytes = (size_t)wN * 2;
    const size_t xb_bytes = (size_t)xN * 2;
    const bool ok2b = (M % 256 == 0) && (N % 128 == 0) && (K % 64 == 0) &&
                      (K >= 64);

    if (ok2b && ws_size >= wb_bytes + xb_bytes) {
        bf16* Wb = (bf16*)d_ws;
        bf16* Xb = (bf16*)((char*)d_ws + wb_bytes);
        dim3 dq_grid((IN / 8 + 127) / 128, OUT);
        k_dequant<<<dq_grid, 128, 0, stream>>>(wq, sc, Wb, IN);
        const long long n8 = xN / 8;
        int cvt_blocks = (int)((n8 + 255) / 256);
        if (cvt_blocks > 2048) cvt_blocks = 2048;
        k_cvt<<<cvt_blocks, 256, 0, stream>>>(x, Xb, n8);
        const int grid = (M / 256) * (N / 128);
        k_gemm2b<<<grid, 512, 0, stream>>>(Xb, Wb, bias, out, M, N, K);
    } else {
        const int grid = (M / 128) * (N / 128);
        k_fused<<<grid, 256, 0, stream>>>(x, wq, sc, bias, out, M, N, K);
    }
}

// Round 10
// 336.422 us; speedup vs baseline: 1.1411x; 1.1411x over previous
//
#include <hip/hip_runtime.h>
#include <hip/hip_bf16.h>
#include <stdint.h>

// DequantingLinear: out[TOK,OUT] = x[TOK,IN] @ dequant(w_q,w_scales)^T + bias
// R10: exact m201 phase ordering. Per phase: reads(p) -> stage 1 unit ->
// [vmcnt(6) at ph4/ph8 only] -> BAR -> lgkmcnt(0) -> 16 MFMA. One barrier
// per phase; reads drain across the barrier-skew; same-phase operand
// consumption (no register double-buffer).

typedef __bf16 bf16;
typedef __bf16 bf16x8 __attribute__((ext_vector_type(8)));
typedef float f32x4 __attribute__((ext_vector_type(4)));

#define AS1 __attribute__((address_space(1)))
#define AS3 __attribute__((address_space(3)))

__device__ __forceinline__ void gload_lds16(const void* g, void* l) {
    __builtin_amdgcn_global_load_lds((AS1 void*)g, (AS3 void*)l, 16, 0, 0);
}

#define MFMA16(d, x, y) d = __builtin_amdgcn_mfma_f32_16x16x32_bf16(x, y, d, 0, 0, 0)

// ---------------- Pass 1a: dequantize w_q (int32) * scale -> bf16 ----------
__global__ __launch_bounds__(128) void k_dequant(
    const int* __restrict__ q, const float* __restrict__ sc,
    bf16* __restrict__ w, int IN) {
    const int row = blockIdx.y;
    const int k = (blockIdx.x * 128 + threadIdx.x) * 8;
    if (k >= IN) return;
    const float s = sc[(size_t)row * (IN >> 5) + (k >> 5)];
    const size_t base = (size_t)row * IN + k;
    const int4 q0 = *(const int4*)(q + base);
    const int4 q1 = *(const int4*)(q + base + 4);
    bf16x8 o;
    o[0] = (bf16)(q0.x * s); o[1] = (bf16)(q0.y * s);
    o[2] = (bf16)(q0.z * s); o[3] = (bf16)(q0.w * s);
    o[4] = (bf16)(q1.x * s); o[5] = (bf16)(q1.y * s);
    o[6] = (bf16)(q1.z * s); o[7] = (bf16)(q1.w * s);
    *(bf16x8*)(w + base) = o;
}

// ---------------- Pass 1b: x f32 -> bf16 -----------------------------------
__global__ __launch_bounds__(256) void k_cvt(
    const float* __restrict__ x, bf16* __restrict__ xb, long long n8) {
    long long i = (long long)blockIdx.x * 256 + threadIdx.x;
    const long long stride = (long long)gridDim.x * 256;
    for (; i < n8; i += stride) {
        const float4 a = *(const float4*)(x + i * 8);
        const float4 b = *(const float4*)(x + i * 8 + 4);
        bf16x8 o;
        o[0] = (bf16)a.x; o[1] = (bf16)a.y; o[2] = (bf16)a.z; o[3] = (bf16)a.w;
        o[4] = (bf16)b.x; o[5] = (bf16)b.y; o[6] = (bf16)b.z; o[7] = (bf16)b.w;
        *(bf16x8*)(xb + i * 8) = o;
    }
}

// ---------------- Pass 2: 256x256 bf16 GEMM, m201-ordered 8-phase ----------
// 512 thr = 8 waves (wm=wv>>2, wn=wv&3); wave out 128x64; acc[8][4].
// LDS buf{0,1} @ {0,65536}: A-k0 @0, A-k1 @16384, B-k0 @32768, B-k1 @49152.
// Unit (16KB): (frow,c4) -> LDSrow=frow>>1, chunk=(((frow&1)<<2)|c4)^(LDSrow&7).
// Phase p: reads(p) [8 or 4 ds_read_b128]; stage 1 unit; [vmcnt(6) @ph4/8];
// BAR; lgkm0; 16 MFMA. Stage FIFO: ph1 A(O,k1), ph2 B(E',k0), ph3 A(E',k0),
// ph4 B(E',k1)+W, ph5 A(E',k1), ph6 B(O',k0), ph7 A(O',k0), ph8 B(O',k1)+W.
__global__ __launch_bounds__(512, 2) void k_gemm8p(
    const bf16* __restrict__ A, const bf16* __restrict__ B,
    const float* __restrict__ bias, float* __restrict__ C,
    int M, int N, int K) {
    __shared__ __align__(16) char lds[131072];
    const int tid = threadIdx.x;
    const int wv = tid >> 6, ln = tid & 63;
    const int wm = wv >> 2, wn = wv & 3;
    const int nbn = N >> 8;
    const int nwg = gridDim.x;
    const int q8 = nwg >> 3, r8 = nwg & 7;
    const int xcd = blockIdx.x & 7, lin = blockIdx.x >> 3;
    const int swz = (xcd < r8 ? xcd * (q8 + 1)
                              : r8 * (q8 + 1) + (xcd - r8) * q8) + lin;
    const int bm = swz / nbn, bn = swz % nbn;

    const size_t rowb = (size_t)K * 2;
    // staging source map (inverse swizzle): slot L -> logical (frow, c4)
    const int L0 = tid, L1 = tid + 512;
    const int x0 = (L0 & 7) ^ ((L0 >> 3) & 7);
    const int x1 = (L1 & 7) ^ ((L1 >> 3) & 7);
    const int fr0 = ((L0 >> 3) << 1) | (x0 >> 2), c40 = x0 & 3;
    const int fr1 = ((L1 >> 3) << 1) | (x1 >> 2), c41 = x1 & 3;
    const char* Asrc0 = (const char*)A + ((size_t)(bm << 8) + fr0) * rowb + c40 * 16;
    const char* Asrc1 = (const char*)A + ((size_t)(bm << 8) + fr1) * rowb + c41 * 16;
    const char* Bsrc0 = (const char*)B + ((size_t)(bn << 8) + fr0) * rowb + c40 * 16;
    const char* Bsrc1 = (const char*)B + ((size_t)(bn << 8) + fr1) * rowb + c41 * 16;
    const int ldsw = wv << 10;

#define STG(bb_, uo_, kt_, P_) do {                                           \
        const size_t kb_ = (size_t)(kt_) << 1;                                \
        gload_lds16(P_##src0 + kb_, lds + (bb_) + (uo_) + ldsw);              \
        gload_lds16(P_##src1 + kb_, lds + (bb_) + (uo_) + 8192 + ldsw);       \
    } while (0)

    // ds_read addressing: chunk per-lane constant
    const int chunk = (((ln & 1) << 2) | (ln >> 4)) ^ ((ln >> 1) & 7);
    const int aoff = (wm << 13) + (((ln & 15) >> 1) << 7) + (chunk << 4);
    const int boff = (wn << 12) + (((ln & 15) >> 1) << 7) + (chunk << 4);

    f32x4 acc[8][4] = {};
    bf16x8 pa[4], pb[4];

#define BAR __builtin_amdgcn_s_barrier()
#define VMW6 asm volatile("s_waitcnt vmcnt(6)" ::: "memory")
#define VMW0 asm volatile("s_waitcnt vmcnt(0)" ::: "memory")
#define NOP0 (void)0

    // phase: reads -> stage -> [wait] -> BAR -> lgkm0 -> MFMA
#define PH(bb_, ks_, h_, RDB_, STAGE_STMT, WAIT_STMT) do {                    \
        _Pragma("unroll")                                                     \
        for (int m = 0; m < 4; ++m)                                           \
            pa[m] = *(const bf16x8*)(lds + (bb_) + (ks_) * 16384 +            \
                                     ((h_) << 12) + aoff + (m << 10));        \
        if (RDB_) {                                                           \
            _Pragma("unroll")                                                 \
            for (int n = 0; n < 4; ++n)                                       \
                pb[n] = *(const bf16x8*)(lds + (bb_) + (ks_) * 16384 + 32768  \
                                         + boff + (n << 10));                 \
        }                                                                     \
        STAGE_STMT;                                                           \
        WAIT_STMT;                                                            \
        BAR;                                                                  \
        asm volatile("s_waitcnt lgkmcnt(0)" ::: "memory");                    \
        __builtin_amdgcn_sched_barrier(0);                                    \
        __builtin_amdgcn_s_setprio(1);                                        \
        _Pragma("unroll")                                                     \
        for (int m = 0; m < 4; ++m)                                           \
            _Pragma("unroll")                                                 \
            for (int n = 0; n < 4; ++n)                                       \
                MFMA16(acc[(h_) * 4 + m][n], pa[m], pb[n]);                   \
        __builtin_amdgcn_s_setprio(0);                                        \
    } while (0)

    // ---- prologue: E=tile0 (4 units) + B(O,k0), A(O,k0), B(O,k1); keep 3 in flight
    STG(0,     0,     0,  A);   // A_E_k0
    STG(0,     32768, 0,  B);   // B_E_k0
    STG(0,     16384, 32, A);   // A_E_k1
    STG(0,     49152, 32, B);   // B_E_k1
    STG(65536, 32768, 64, B);   // B_O_k0
    STG(65536, 0,     64, A);   // A_O_k0
    STG(65536, 49152, 96, B);   // B_O_k1
    VMW6;   // drain the 4 E units; keep O's 3 units (6 loads) in flight
    BAR;

    const int NI = K >> 7;
#pragma unroll 1
    for (int j = 0; j < NI - 1; ++j) {
        const int kO1 = (j << 7) + 96;    // A(O,k1) col
        const int kE2 = (j << 7) + 128;   // next even tile
        const int kO2 = (j << 7) + 192;   // next odd tile
        PH(0,     0, 0, 1, STG(65536, 16384, kO1,      A), NOP0);  // ph1
        PH(0,     0, 1, 0, STG(0,     32768, kE2,      B), NOP0);  // ph2
        PH(0,     1, 0, 1, STG(0,     0,     kE2,      A), NOP0);  // ph3
        PH(0,     1, 1, 0, STG(0,     49152, kE2 + 32, B), VMW6);  // ph4
        PH(65536, 0, 0, 1, STG(0,     16384, kE2 + 32, A), NOP0);  // ph5
        PH(65536, 0, 1, 0, STG(65536, 32768, kO2,      B), NOP0);  // ph6
        PH(65536, 1, 0, 1, STG(65536, 0,     kO2,      A), NOP0);  // ph7
        PH(65536, 1, 1, 0, STG(65536, 49152, kO2 + 32, B), VMW6);  // ph8
    }
    {   // last iteration: only A(O,k1) staged; drain fully at ph4
        const int kO1 = ((NI - 1) << 7) + 96;
        PH(0,     0, 0, 1, STG(65536, 16384, kO1, A), NOP0);
        PH(0,     0, 1, 0, NOP0,                      NOP0);
        PH(0,     1, 0, 1, NOP0,                      NOP0);
        PH(0,     1, 1, 0, NOP0,                      VMW0);
        PH(65536, 0, 0, 1, NOP0,                      NOP0);
        PH(65536, 0, 1, 0, NOP0,                      NOP0);
        PH(65536, 1, 0, 1, NOP0,                      NOP0);
        PH(65536, 1, 1, 0, NOP0,                      NOP0);
    }
#undef PH
#undef STG

    // ---- epilogue: D layout col=lane&15, row=(lane>>4)*4+reg
    const int erow = (bm << 8) + (wm << 7) + ((ln >> 4) << 2);
    const int ecol = (bn << 8) + (wn << 6) + (ln & 15);
    float bv[4];
#pragma unroll
    for (int n = 0; n < 4; ++n) bv[n] = bias[ecol + (n << 4)];
#pragma unroll
    for (int m = 0; m < 8; ++m)
#pragma unroll
        for (int r = 0; r < 4; ++r) {
            float* Crow = C + (size_t)(erow + (m << 4) + r) * N + ecol;
#pragma unroll
            for (int n = 0; n < 4; ++n)
                Crow[n << 4] = acc[m][n][r] + bv[n];
        }
}

// ---------------- Fallback: fused dequant+GEMM (no workspace) --------------
__global__ __launch_bounds__(256) void k_fused(
    const float* __restrict__ X, const int* __restrict__ Q,
    const float* __restrict__ SC, const float* __restrict__ bias,
    float* __restrict__ C, int M, int N, int K) {
    __shared__ __align__(16) bf16 sA[128 * 32];
    __shared__ __align__(16) bf16 sB[128 * 32];
    const int tid = threadIdx.x;
    const int wv = tid >> 6;
    const int ln = tid & 63;
    const int nbn = N >> 7;
    const int nwg = gridDim.x;
    const int q8 = nwg >> 3, r8 = nwg & 7;
    const int xcd = blockIdx.x & 7, lin = blockIdx.x >> 3;
    const int swz = (xcd < r8 ? xcd * (q8 + 1)
                              : r8 * (q8 + 1) + (xcd - r8) * q8) + lin;
    const int bm = swz / nbn, bn = swz % nbn;
    const int wr = (wv >> 1) << 6;
    const int wc = (wv & 1) << 6;
    const int srow = tid >> 1;
    const int sk = (tid & 1) << 4;

    f32x4 acc[4][4] = {};
    const float* xrow = X + (size_t)((bm << 7) + srow) * K + sk;
    const int* qrow = Q + (size_t)((bn << 7) + srow) * K + sk;
    const float* scrow = SC + (size_t)((bn << 7) + srow) * (K >> 5);

    for (int kt = 0; kt < K; kt += 32) {
        const float4 a0 = *(const float4*)(xrow + kt);
        const float4 a1 = *(const float4*)(xrow + kt + 4);
        const float4 a2 = *(const float4*)(xrow + kt + 8);
        const float4 a3 = *(const float4*)(xrow + kt + 12);
        const int4 q0 = *(const int4*)(qrow + kt);
        const int4 q1 = *(const int4*)(qrow + kt + 4);
        const int4 q2 = *(const int4*)(qrow + kt + 8);
        const int4 q3 = *(const int4*)(qrow + kt + 12);
        const float s = scrow[(kt + sk) >> 5];
        bf16x8 wa0, wa1, wb0, wb1;
        wa0[0] = (bf16)a0.x; wa0[1] = (bf16)a0.y; wa0[2] = (bf16)a0.z; wa0[3] = (bf16)a0.w;
        wa0[4] = (bf16)a1.x; wa0[5] = (bf16)a1.y; wa0[6] = (bf16)a1.z; wa0[7] = (bf16)a1.w;
        wa1[0] = (bf16)a2.x; wa1[1] = (bf16)a2.y; wa1[2] = (bf16)a2.z; wa1[3] = (bf16)a2.w;
        wa1[4] = (bf16)a3.x; wa1[5] = (bf16)a3.y; wa1[6] = (bf16)a3.z; wa1[7] = (bf16)a3.w;
        wb0[0] = (bf16)(q0.x * s); wb0[1] = (bf16)(q0.y * s);
        wb0[2] = (bf16)(q0.z * s); wb0[3] = (bf16)(q0.w * s);
        wb0[4] = (bf16)(q1.x * s); wb0[5] = (bf16)(q1.y * s);
        wb0[6] = (bf16)(q1.z * s); wb0[7] = (bf16)(q1.w * s);
        wb1[0] = (bf16)(q2.x * s); wb1[1] = (bf16)(q2.y * s);
        wb1[2] = (bf16)(q2.z * s); wb1[3] = (bf16)(q2.w * s);
        wb1[4] = (bf16)(q3.x * s); wb1[5] = (bf16)(q3.y * s);
        wb1[6] = (bf16)(q3.z * s); wb1[7] = (bf16)(q3.w * s);
        __syncthreads();
        *(bf16x8*)(sA + srow * 32 + sk) = wa0;
        *(bf16x8*)(sA + srow * 32 + sk + 8) = wa1;
        *(bf16x8*)(sB + srow * 32 + sk) = wb0;
        *(bf16x8*)(sB + srow * 32 + sk + 8) = wb1;
        __syncthreads();

        bf16x8 af[4], bg[4];
#pragma unroll
        for (int m = 0; m < 4; ++m)
            af[m] = *(const bf16x8*)(sA + ((wr + (m << 4) + (ln & 15)) << 5) +
                                     ((ln >> 4) << 3));
#pragma unroll
        for (int n = 0; n < 4; ++n)
            bg[n] = *(const bf16x8*)(sB + ((wc + (n << 4) + (ln & 15)) << 5) +
                                     ((ln >> 4) << 3));
#pragma unroll
        for (int m = 0; m < 4; ++m)
#pragma unroll
            for (int n = 0; n < 4; ++n)
                acc[m][n] = __builtin_amdgcn_mfma_f32_16x16x32_bf16(
                    af[m], bg[n], acc[m][n], 0, 0, 0);
    }

    float bv[4];
#pragma unroll
    for (int n = 0; n < 4; ++n)
        bv[n] = bias[(bn << 7) + wc + (n << 4) + (ln & 15)];
#pragma unroll
    for (int m = 0; m < 4; ++m) {
        const int grow0 = (bm << 7) + wr + (m << 4) + ((ln >> 4) << 2);
#pragma unroll
        for (int r = 0; r < 4; ++r) {
            float* Crow = C + (size_t)(grow0 + r) * N;
#pragma unroll
            for (int n = 0; n < 4; ++n)
                Crow[(bn << 7) + wc + (n << 4) + (ln & 15)] =
                    acc[m][n][r] + bv[n];
        }
    }
}

extern "C" void kernel_launch(void* const* d_in, const int* in_sizes, int n_in,
                              void* d_out, int out_size, void* d_ws, size_t ws_size,
                              hipStream_t stream) {
    const float* x = (const float*)d_in[0];
    const int* wq = (const int*)d_in[1];
    const float* sc = (const float*)d_in[2];
    const float* bias = (const float*)d_in[3];
    float* out = (float*)d_out;

    const long long xN = in_sizes[0];  // TOK*IN
    const long long wN = in_sizes[1];  // OUT*IN
    const int OUT = in_sizes[3];       // bias length
    const int IN = (int)(wN / OUT);
    const int TOK = (int)(xN / IN);
    const int M = TOK, N = OUT, K = IN;

    const size_t wb_bytes = (size_t)wN * 2;
    const size_t xb_bytes = (size_t)xN * 2;
    const bool ok8p = (M % 256 == 0) && (N % 256 == 0) && (K % 128 == 0) &&
                      (K >= 256);

    if (ok8p && ws_size >= wb_bytes + xb_bytes) {
        bf16* Wb = (bf16*)d_ws;
        bf16* Xb = (bf16*)((char*)d_ws + wb_bytes);
        dim3 dq_grid((IN / 8 + 127) / 128, OUT);
        k_dequant<<<dq_grid, 128, 0, stream>>>(wq, sc, Wb, IN);
        const long long n8 = xN / 8;
        int cvt_blocks = (int)((n8 + 255) / 256);
        if (cvt_blocks > 2048) cvt_blocks = 2048;
        k_cvt<<<cvt_blocks, 256, 0, stream>>>(x, Xb, n8);
        const int grid = (M / 256) * (N / 256);
        k_gemm8p<<<grid, 512, 0, stream>>>(Xb, Wb, bias, out, M, N, K);
    } else {
        const int grid = (M / 128) * (N / 128);
        k_fused<<<grid, 256, 0, stream>>>(x, wq, sc, bias, out, M, N, K);
    }
}

// Round 11
// 336.252 us; speedup vs baseline: 1.1417x; 1.0005x over previous
//
#include <hip/hip_runtime.h>
#include <hip/hip_bf16.h>
#include <stdint.h>

// DequantingLinear: out[TOK,OUT] = x[TOK,IN] @ dequant(w_q,w_scales)^T + bias
// R11 = R10 + NON-TEMPORAL C stores. The 201MB C stream was churning L3 and
// evicting B (75.5MB) between block-waves -> FETCH 615MB vs ~100MB ideal ->
// vmcnt(6) stalls on refetched B. nt stores keep A/B L3-resident.

typedef __bf16 bf16;
typedef __bf16 bf16x8 __attribute__((ext_vector_type(8)));
typedef float f32x4 __attribute__((ext_vector_type(4)));

#define AS1 __attribute__((address_space(1)))
#define AS3 __attribute__((address_space(3)))

__device__ __forceinline__ void gload_lds16(const void* g, void* l) {
    __builtin_amdgcn_global_load_lds((AS1 void*)g, (AS3 void*)l, 16, 0, 0);
}

#define MFMA16(d, x, y) d = __builtin_amdgcn_mfma_f32_16x16x32_bf16(x, y, d, 0, 0, 0)

// ---------------- Pass 1a: dequantize w_q (int32) * scale -> bf16 ----------
__global__ __launch_bounds__(128) void k_dequant(
    const int* __restrict__ q, const float* __restrict__ sc,
    bf16* __restrict__ w, int IN) {
    const int row = blockIdx.y;
    const int k = (blockIdx.x * 128 + threadIdx.x) * 8;
    if (k >= IN) return;
    const float s = sc[(size_t)row * (IN >> 5) + (k >> 5)];
    const size_t base = (size_t)row * IN + k;
    const int4 q0 = *(const int4*)(q + base);
    const int4 q1 = *(const int4*)(q + base + 4);
    bf16x8 o;
    o[0] = (bf16)(q0.x * s); o[1] = (bf16)(q0.y * s);
    o[2] = (bf16)(q0.z * s); o[3] = (bf16)(q0.w * s);
    o[4] = (bf16)(q1.x * s); o[5] = (bf16)(q1.y * s);
    o[6] = (bf16)(q1.z * s); o[7] = (bf16)(q1.w * s);
    *(bf16x8*)(w + base) = o;
}

// ---------------- Pass 1b: x f32 -> bf16 -----------------------------------
__global__ __launch_bounds__(256) void k_cvt(
    const float* __restrict__ x, bf16* __restrict__ xb, long long n8) {
    long long i = (long long)blockIdx.x * 256 + threadIdx.x;
    const long long stride = (long long)gridDim.x * 256;
    for (; i < n8; i += stride) {
        const float4 a = *(const float4*)(x + i * 8);
        const float4 b = *(const float4*)(x + i * 8 + 4);
        bf16x8 o;
        o[0] = (bf16)a.x; o[1] = (bf16)a.y; o[2] = (bf16)a.z; o[3] = (bf16)a.w;
        o[4] = (bf16)b.x; o[5] = (bf16)b.y; o[6] = (bf16)b.z; o[7] = (bf16)b.w;
        *(bf16x8*)(xb + i * 8) = o;
    }
}

// ---------------- Pass 2: 256x256 bf16 GEMM, m201-ordered 8-phase ----------
// Identical to R10 except the epilogue uses nontemporal stores.
__global__ __launch_bounds__(512, 2) void k_gemm8p(
    const bf16* __restrict__ A, const bf16* __restrict__ B,
    const float* __restrict__ bias, float* __restrict__ C,
    int M, int N, int K) {
    __shared__ __align__(16) char lds[131072];
    const int tid = threadIdx.x;
    const int wv = tid >> 6, ln = tid & 63;
    const int wm = wv >> 2, wn = wv & 3;
    const int nbn = N >> 8;
    const int nwg = gridDim.x;
    const int q8 = nwg >> 3, r8 = nwg & 7;
    const int xcd = blockIdx.x & 7, lin = blockIdx.x >> 3;
    const int swz = (xcd < r8 ? xcd * (q8 + 1)
                              : r8 * (q8 + 1) + (xcd - r8) * q8) + lin;
    const int bm = swz / nbn, bn = swz % nbn;

    const size_t rowb = (size_t)K * 2;
    const int L0 = tid, L1 = tid + 512;
    const int x0 = (L0 & 7) ^ ((L0 >> 3) & 7);
    const int x1 = (L1 & 7) ^ ((L1 >> 3) & 7);
    const int fr0 = ((L0 >> 3) << 1) | (x0 >> 2), c40 = x0 & 3;
    const int fr1 = ((L1 >> 3) << 1) | (x1 >> 2), c41 = x1 & 3;
    const char* Asrc0 = (const char*)A + ((size_t)(bm << 8) + fr0) * rowb + c40 * 16;
    const char* Asrc1 = (const char*)A + ((size_t)(bm << 8) + fr1) * rowb + c41 * 16;
    const char* Bsrc0 = (const char*)B + ((size_t)(bn << 8) + fr0) * rowb + c40 * 16;
    const char* Bsrc1 = (const char*)B + ((size_t)(bn << 8) + fr1) * rowb + c41 * 16;
    const int ldsw = wv << 10;

#define STG(bb_, uo_, kt_, P_) do {                                           \
        const size_t kb_ = (size_t)(kt_) << 1;                                \
        gload_lds16(P_##src0 + kb_, lds + (bb_) + (uo_) + ldsw);              \
        gload_lds16(P_##src1 + kb_, lds + (bb_) + (uo_) + 8192 + ldsw);       \
    } while (0)

    const int chunk = (((ln & 1) << 2) | (ln >> 4)) ^ ((ln >> 1) & 7);
    const int aoff = (wm << 13) + (((ln & 15) >> 1) << 7) + (chunk << 4);
    const int boff = (wn << 12) + (((ln & 15) >> 1) << 7) + (chunk << 4);

    f32x4 acc[8][4] = {};
    bf16x8 pa[4], pb[4];

#define BAR __builtin_amdgcn_s_barrier()
#define VMW6 asm volatile("s_waitcnt vmcnt(6)" ::: "memory")
#define VMW0 asm volatile("s_waitcnt vmcnt(0)" ::: "memory")
#define NOP0 (void)0

#define PH(bb_, ks_, h_, RDB_, STAGE_STMT, WAIT_STMT) do {                    \
        _Pragma("unroll")                                                     \
        for (int m = 0; m < 4; ++m)                                           \
            pa[m] = *(const bf16x8*)(lds + (bb_) + (ks_) * 16384 +            \
                                     ((h_) << 12) + aoff + (m << 10));        \
        if (RDB_) {                                                           \
            _Pragma("unroll")                                                 \
            for (int n = 0; n < 4; ++n)                                       \
                pb[n] = *(const bf16x8*)(lds + (bb_) + (ks_) * 16384 + 32768  \
                                         + boff + (n << 10));                 \
        }                                                                     \
        STAGE_STMT;                                                           \
        WAIT_STMT;                                                            \
        BAR;                                                                  \
        asm volatile("s_waitcnt lgkmcnt(0)" ::: "memory");                    \
        __builtin_amdgcn_sched_barrier(0);                                    \
        __builtin_amdgcn_s_setprio(1);                                        \
        _Pragma("unroll")                                                     \
        for (int m = 0; m < 4; ++m)                                           \
            _Pragma("unroll")                                                 \
            for (int n = 0; n < 4; ++n)                                       \
                MFMA16(acc[(h_) * 4 + m][n], pa[m], pb[n]);                   \
        __builtin_amdgcn_s_setprio(0);                                        \
    } while (0)

    // ---- prologue
    STG(0,     0,     0,  A);
    STG(0,     32768, 0,  B);
    STG(0,     16384, 32, A);
    STG(0,     49152, 32, B);
    STG(65536, 32768, 64, B);
    STG(65536, 0,     64, A);
    STG(65536, 49152, 96, B);
    VMW6;
    BAR;

    const int NI = K >> 7;
#pragma unroll 1
    for (int j = 0; j < NI - 1; ++j) {
        const int kO1 = (j << 7) + 96;
        const int kE2 = (j << 7) + 128;
        const int kO2 = (j << 7) + 192;
        PH(0,     0, 0, 1, STG(65536, 16384, kO1,      A), NOP0);  // ph1
        PH(0,     0, 1, 0, STG(0,     32768, kE2,      B), NOP0);  // ph2
        PH(0,     1, 0, 1, STG(0,     0,     kE2,      A), NOP0);  // ph3
        PH(0,     1, 1, 0, STG(0,     49152, kE2 + 32, B), VMW6);  // ph4
        PH(65536, 0, 0, 1, STG(0,     16384, kE2 + 32, A), NOP0);  // ph5
        PH(65536, 0, 1, 0, STG(65536, 32768, kO2,      B), NOP0);  // ph6
        PH(65536, 1, 0, 1, STG(65536, 0,     kO2,      A), NOP0);  // ph7
        PH(65536, 1, 1, 0, STG(65536, 49152, kO2 + 32, B), VMW6);  // ph8
    }
    {
        const int kO1 = ((NI - 1) << 7) + 96;
        PH(0,     0, 0, 1, STG(65536, 16384, kO1, A), NOP0);
        PH(0,     0, 1, 0, NOP0,                      NOP0);
        PH(0,     1, 0, 1, NOP0,                      NOP0);
        PH(0,     1, 1, 0, NOP0,                      VMW0);
        PH(65536, 0, 0, 1, NOP0,                      NOP0);
        PH(65536, 0, 1, 0, NOP0,                      NOP0);
        PH(65536, 1, 0, 1, NOP0,                      NOP0);
        PH(65536, 1, 1, 0, NOP0,                      NOP0);
    }
#undef PH
#undef STG

    // ---- epilogue: nontemporal C stores (bypass L2/L3 retention)
    const int erow = (bm << 8) + (wm << 7) + ((ln >> 4) << 2);
    const int ecol = (bn << 8) + (wn << 6) + (ln & 15);
    float bv[4];
#pragma unroll
    for (int n = 0; n < 4; ++n) bv[n] = bias[ecol + (n << 4)];
#pragma unroll
    for (int m = 0; m < 8; ++m)
#pragma unroll
        for (int r = 0; r < 4; ++r) {
            float* Crow = C + (size_t)(erow + (m << 4) + r) * N + ecol;
#pragma unroll
            for (int n = 0; n < 4; ++n)
                __builtin_nontemporal_store(acc[m][n][r] + bv[n],
                                            &Crow[n << 4]);
        }
}

// ---------------- Fallback: fused dequant+GEMM (no workspace) --------------
__global__ __launch_bounds__(256) void k_fused(
    const float* __restrict__ X, const int* __restrict__ Q,
    const float* __restrict__ SC, const float* __restrict__ bias,
    float* __restrict__ C, int M, int N, int K) {
    __shared__ __align__(16) bf16 sA[128 * 32];
    __shared__ __align__(16) bf16 sB[128 * 32];
    const int tid = threadIdx.x;
    const int wv = tid >> 6;
    const int ln = tid & 63;
    const int nbn = N >> 7;
    const int nwg = gridDim.x;
    const int q8 = nwg >> 3, r8 = nwg & 7;
    const int xcd = blockIdx.x & 7, lin = blockIdx.x >> 3;
    const int swz = (xcd < r8 ? xcd * (q8 + 1)
                              : r8 * (q8 + 1) + (xcd - r8) * q8) + lin;
    const int bm = swz / nbn, bn = swz % nbn;
    const int wr = (wv >> 1) << 6;
    const int wc = (wv & 1) << 6;
    const int srow = tid >> 1;
    const int sk = (tid & 1) << 4;

    f32x4 acc[4][4] = {};
    const float* xrow = X + (size_t)((bm << 7) + srow) * K + sk;
    const int* qrow = Q + (size_t)((bn << 7) + srow) * K + sk;
    const float* scrow = SC + (size_t)((bn << 7) + srow) * (K >> 5);

    for (int kt = 0; kt < K; kt += 32) {
        const float4 a0 = *(const float4*)(xrow + kt);
        const float4 a1 = *(const float4*)(xrow + kt + 4);
        const float4 a2 = *(const float4*)(xrow + kt + 8);
        const float4 a3 = *(const float4*)(xrow + kt + 12);
        const int4 q0 = *(const int4*)(qrow + kt);
        const int4 q1 = *(const int4*)(qrow + kt + 4);
        const int4 q2 = *(const int4*)(qrow + kt + 8);
        const int4 q3 = *(const int4*)(qrow + kt + 12);
        const float s = scrow[(kt + sk) >> 5];
        bf16x8 wa0, wa1, wb0, wb1;
        wa0[0] = (bf16)a0.x; wa0[1] = (bf16)a0.y; wa0[2] = (bf16)a0.z; wa0[3] = (bf16)a0.w;
        wa0[4] = (bf16)a1.x; wa0[5] = (bf16)a1.y; wa0[6] = (bf16)a1.z; wa0[7] = (bf16)a1.w;
        wa1[0] = (bf16)a2.x; wa1[1] = (bf16)a2.y; wa1[2] = (bf16)a2.z; wa1[3] = (bf16)a2.w;
        wa1[4] = (bf16)a3.x; wa1[5] = (bf16)a3.y; wa1[6] = (bf16)a3.z; wa1[7] = (bf16)a3.w;
        wb0[0] = (bf16)(q0.x * s); wb0[1] = (bf16)(q0.y * s);
        wb0[2] = (bf16)(q0.z * s); wb0[3] = (bf16)(q0.w * s);
        wb0[4] = (bf16)(q1.x * s); wb0[5] = (bf16)(q1.y * s);
        wb0[6] = (bf16)(q1.z * s); wb0[7] = (bf16)(q1.w * s);
        wb1[0] = (bf16)(q2.x * s); wb1[1] = (bf16)(q2.y * s);
        wb1[2] = (bf16)(q2.z * s); wb1[3] = (bf16)(q2.w * s);
        wb1[4] = (bf16)(q3.x * s); wb1[5] = (bf16)(q3.y * s);
        wb1[6] = (bf16)(q3.z * s); wb1[7] = (bf16)(q3.w * s);
        __syncthreads();
        *(bf16x8*)(sA + srow * 32 + sk) = wa0;
        *(bf16x8*)(sA + srow * 32 + sk + 8) = wa1;
        *(bf16x8*)(sB + srow * 32 + sk) = wb0;
        *(bf16x8*)(sB + srow * 32 + sk + 8) = wb1;
        __syncthreads();

        bf16x8 af[4], bg[4];
#pragma unroll
        for (int m = 0; m < 4; ++m)
            af[m] = *(const bf16x8*)(sA + ((wr + (m << 4) + (ln & 15)) << 5) +
                                     ((ln >> 4) << 3));
#pragma unroll
        for (int n = 0; n < 4; ++n)
            bg[n] = *(const bf16x8*)(sB + ((wc + (n << 4) + (ln & 15)) << 5) +
                                     ((ln >> 4) << 3));
#pragma unroll
        for (int m = 0; m < 4; ++m)
#pragma unroll
            for (int n = 0; n < 4; ++n)
                acc[m][n] = __builtin_amdgcn_mfma_f32_16x16x32_bf16(
                    af[m], bg[n], acc[m][n], 0, 0, 0);
    }

    float bv[4];
#pragma unroll
    for (int n = 0; n < 4; ++n)
        bv[n] = bias[(bn << 7) + wc + (n << 4) + (ln & 15)];
#pragma unroll
    for (int m = 0; m < 4; ++m) {
        const int grow0 = (bm << 7) + wr + (m << 4) + ((ln >> 4) << 2);
#pragma unroll
        for (int r = 0; r < 4; ++r) {
            float* Crow = C + (size_t)(grow0 + r) * N;
#pragma unroll
            for (int n = 0; n < 4; ++n)
                Crow[(bn << 7) + wc + (n << 4) + (ln & 15)] =
                    acc[m][n][r] + bv[n];
        }
    }
}

extern "C" void kernel_launch(void* const* d_in, const int* in_sizes, int n_in,
                              void* d_out, int out_size, void* d_ws, size_t ws_size,
                              hipStream_t stream) {
    const float* x = (const float*)d_in[0];
    const int* wq = (const int*)d_in[1];
    const float* sc = (const float*)d_in[2];
    const float* bias = (const float*)d_in[3];
    float* out = (float*)d_out;

    const long long xN = in_sizes[0];  // TOK*IN
    const long long wN = in_sizes[1];  // OUT*IN
    const int OUT = in_sizes[3];       // bias length
    const int IN = (int)(wN / OUT);
    const int TOK = (int)(xN / IN);
    const int M = TOK, N = OUT, K = IN;

    const size_t wb_bytes = (size_t)wN * 2;
    const size_t xb_bytes = (size_t)xN * 2;
    const bool ok8p = (M % 256 == 0) && (N % 256 == 0) && (K % 128 == 0) &&
                      (K >= 256);

    if (ok8p && ws_size >= wb_bytes + xb_bytes) {
        bf16* Wb = (bf16*)d_ws;
        bf16* Xb = (bf16*)((char*)d_ws + wb_bytes);
        dim3 dq_grid((IN / 8 + 127) / 128, OUT);
        k_dequant<<<dq_grid, 128, 0, stream>>>(wq, sc, Wb, IN);
        const long long n8 = xN / 8;
        int cvt_blocks = (int)((n8 + 255) / 256);
        if (cvt_blocks > 2048) cvt_blocks = 2048;
        k_cvt<<<cvt_blocks, 256, 0, stream>>>(x, Xb, n8);
        const int grid = (M / 256) * (N / 256);
        k_gemm8p<<<grid, 512, 0, stream>>>(Xb, Wb, bias, out, M, N, K);
    } else {
        const int grid = (M / 128) * (N / 128);
        k_fused<<<grid, 256, 0, stream>>>(x, wq, sc, bias, out, M, N, K);
    }
}